// Round 5
// baseline (209.428 us; speedup 1.0000x reference)
//
#include <hip/hip_runtime.h>

// Problem constants (B=8, C=256, H=W=128, L=512)
#define BATCH 8
#define CIN   256
#define LDIM  512
#define HDIM  128
#define WDIM  128
#define HWN   (HDIM * WDIM)      // 16384
#define PH    64                  // prev_rgb spatial
#define PW    64

// ---------------------------------------------------------------------------
// Kernel 1: style = istyle @ style_w.T + style_b ; wmod[b,o,c] = conv_w[o,c]*(style+1)
// grid = BATCH*CIN blocks of 64 threads (1 wave each). Coalesced over L.
// ---------------------------------------------------------------------------
__global__ __launch_bounds__(64)
void style_weights_kernel(const float* __restrict__ istyle,   // [B, L]
                          const float* __restrict__ style_w,  // [C, L]
                          const float* __restrict__ style_b,  // [C]
                          const float* __restrict__ conv_w,   // [3, C]
                          float* __restrict__ wmod) {         // [B, 3, C]
    const int bid = blockIdx.x;          // 0 .. B*C-1
    const int b = bid >> 8;              // bid / CIN
    const int c = bid & (CIN - 1);
    const int t = threadIdx.x;           // 0..63

    const float* is = istyle + b * LDIM;
    const float* sw = style_w + c * LDIM;

    float p = 0.0f;
#pragma unroll
    for (int l = t; l < LDIM; l += 64) p += is[l] * sw[l];

    // wave64 butterfly reduce
#pragma unroll
    for (int off = 32; off > 0; off >>= 1) p += __shfl_down(p, off);

    if (t == 0) {
        const float s = p + style_b[c] + 1.0f;
        wmod[(b * 3 + 0) * CIN + c] = conv_w[0 * CIN + c] * s;
        wmod[(b * 3 + 1) * CIN + c] = conv_w[1 * CIN + c] * s;
        wmod[(b * 3 + 2) * CIN + c] = conv_w[2 * CIN + c] * s;
    }
}

// ---------------------------------------------------------------------------
// Kernel 2: out[b,o,pos] = sum_c wmod[b,o,c]*x[b,c,pos] + rgb_bias[o] + upsample
// Single-wave blocks (64 thr), 2 positions per thread via float2 loads.
// 128 pos/block -> grid = 8*16384/128 = 1024 blocks = 4 blocks/CU.
// ---------------------------------------------------------------------------
__global__ __launch_bounds__(64)
void rgb_main_kernel(const float* __restrict__ x,        // [B, C, H, W]
                     const float* __restrict__ prev,     // [B, 3, 64, 64]
                     const float* __restrict__ rgb_bias, // [3]
                     const float* __restrict__ wmod,     // [B, 3, C]
                     float* __restrict__ out) {          // [B, 3, H, W]
    __shared__ float sw[3 * CIN];

    const int t    = threadIdx.x;                 // 0..63
    const int flat = blockIdx.x * 128;            // 128 pos per block; 128 | 16384
    const int b    = flat >> 14;                  // flat / HWN
    const int pos  = (flat & (HWN - 1)) + t * 2;  // even spatial position

    // stage this batch's 768 modulated weights into LDS (12 loads/lane)
#pragma unroll
    for (int i = t; i < 3 * CIN; i += 64)
        sw[i] = wmod[b * 3 * CIN + i];
    __syncthreads();

    const float2* xp = (const float2*)(x + ((size_t)b * CIN) * HWN + pos);

    float a00 = 0.f, a01 = 0.f, a10 = 0.f, a11 = 0.f, a20 = 0.f, a21 = 0.f;
#pragma unroll 16
    for (int c = 0; c < CIN; ++c) {
        const float2 v = xp[(size_t)c * (HWN / 2)];  // 512 B per wave-instr
        const float w0 = sw[c];                      // LDS same-address broadcast
        const float w1 = sw[CIN + c];
        const float w2 = sw[2 * CIN + c];
        a00 += v.x * w0; a01 += v.y * w0;
        a10 += v.x * w1; a11 += v.y * w1;
        a20 += v.x * w2; a21 += v.y * w2;
    }

    // --- bilinear x2 upsample, half-pixel centers, edge clamp (two pixels) ---
    const int h = pos >> 7;
    const int w = pos & (WDIM - 1);          // even; pair is (w, w+1)

    const float shf = h * 0.5f - 0.25f;
    const float fh  = shf - floorf(shf);     // 0.25 or 0.75
    int h0 = (int)floorf(shf);
    int h1 = min(h0 + 1, PH - 1);
    h0 = max(h0, 0);

    // w even = 2k: w0=k-1 (clamped), fw=0.75 ; w+1 = 2k+1: w0=k, fw=0.25
    const int k = w >> 1;
    const int wa0 = max(k - 1, 0), wa1 = k;            // for even pixel
    const float fwa = 0.75f;
    const int wb0 = k, wb1 = min(k + 1, PW - 1);       // for odd pixel
    const float fwb = 0.25f;

    const float* pb = prev + (size_t)b * 3 * PH * PW;
    float upx[3], upy[3];
#pragma unroll
    for (int o = 0; o < 3; ++o) {
        const float* p0 = pb + o * PH * PW + h0 * PW;
        const float* p1 = pb + o * PH * PW + h1 * PW;
        // even pixel
        {
            const float top = p0[wa0] + (p0[wa1] - p0[wa0]) * fwa;
            const float bot = p1[wa0] + (p1[wa1] - p1[wa0]) * fwa;
            upx[o] = top + (bot - top) * fh;
        }
        // odd pixel
        {
            const float top = p0[wb0] + (p0[wb1] - p0[wb0]) * fwb;
            const float bot = p1[wb0] + (p1[wb1] - p1[wb0]) * fwb;
            upy[o] = top + (bot - top) * fh;
        }
    }

    float2* op = (float2*)(out + ((size_t)b * 3) * HWN + pos);
    const float b0 = rgb_bias[0], b1 = rgb_bias[1], b2 = rgb_bias[2];
    op[0]           = make_float2(a00 + b0 + upx[0], a01 + b0 + upy[0]);
    op[HWN / 2]     = make_float2(a10 + b1 + upx[1], a11 + b1 + upy[1]);
    op[HWN]         = make_float2(a20 + b2 + upx[2], a21 + b2 + upy[2]);
}

// ---------------------------------------------------------------------------
extern "C" void kernel_launch(void* const* d_in, const int* in_sizes, int n_in,
                              void* d_out, int out_size, void* d_ws, size_t ws_size,
                              hipStream_t stream) {
    const float* x        = (const float*)d_in[0];  // [8,256,128,128]
    const float* prev_rgb = (const float*)d_in[1];  // [8,3,64,64]
    const float* istyle   = (const float*)d_in[2];  // [8,512]
    const float* style_w  = (const float*)d_in[3];  // [256,512]
    const float* style_b  = (const float*)d_in[4];  // [256]
    const float* conv_w   = (const float*)d_in[5];  // [3,256]
    const float* rgb_bias = (const float*)d_in[6];  // [3]
    float* out = (float*)d_out;
    float* wmod = (float*)d_ws;                     // [8,3,256] = 24 KB

    style_weights_kernel<<<BATCH * CIN, 64, 0, stream>>>(
        istyle, style_w, style_b, conv_w, wmod);

    rgb_main_kernel<<<(BATCH * HWN) / 128, 64, 0, stream>>>(
        x, prev_rgb, rgb_bias, wmod, out);
}